// Round 13
// baseline (715.636 us; speedup 1.0000x reference)
//
#include <hip/hip_runtime.h>

#define TT     128
#define NBATCH 64

// raw barrier: drain this wave's LDS ops, then barrier. No vmcnt drain --
// keeps async Qt prefetch in flight across phases.
#define BAR()  asm volatile("s_waitcnt lgkmcnt(0)\n\ts_barrier" ::: "memory")
#define BARV() asm volatile("s_waitcnt vmcnt(0) lgkmcnt(0)\n\ts_barrier" ::: "memory")

__device__ __forceinline__ void gload16(const float* g, float* l) {
    __builtin_amdgcn_global_load_lds(
        (__attribute__((address_space(1))) void*)g,
        (__attribute__((address_space(3))) void*)l, 16, 0, 0);
}

// SALU broadcast: read lane `l`'s value of v (l compile-time constant)
__device__ __forceinline__ float rdlane(float v, int l) {
    return __int_as_float(__builtin_amdgcn_readlane(__float_as_int(v), l));
}

// closed-form 4x4 inverse via 2x2 blocks (SPD pivot blocks, no pivoting)
__device__ __forceinline__ void inv4(const float4 pr[4], float IP[4][4]) {
    float a00=pr[0].x, a01=pr[0].y, a10=pr[1].x, a11=pr[1].y;
    float b00=pr[0].z, b01=pr[0].w, b10=pr[1].z, b11=pr[1].w;
    float c00=pr[2].x, c01=pr[2].y, c10=pr[3].x, c11=pr[3].y;
    float d00=pr[2].z, d01=pr[2].w, d10=pr[3].z, d11=pr[3].w;
    float r = 1.0f / (a00*a11 - a01*a10);
    float ia00 =  a11*r, ia01 = -a01*r, ia10 = -a10*r, ia11 = a00*r;
    float t00 = ia00*b00 + ia01*b10, t01 = ia00*b01 + ia01*b11;
    float t10 = ia10*b00 + ia11*b10, t11 = ia10*b01 + ia11*b11;
    float u00 = c00*ia00 + c01*ia10, u01 = c00*ia01 + c01*ia11;
    float u10 = c10*ia00 + c11*ia10, u11 = c10*ia01 + c11*ia11;
    float s00 = d00 - (c00*t00 + c01*t10), s01 = d01 - (c00*t01 + c01*t11);
    float s10 = d10 - (c10*t00 + c11*t10), s11 = d11 - (c10*t01 + c11*t11);
    float rs = 1.0f / (s00*s11 - s01*s10);
    float is00 =  s11*rs, is01 = -s01*rs, is10 = -s10*rs, is11 = s00*rs;
    float su00 = is00*u00 + is01*u10, su01 = is00*u01 + is01*u11;
    float su10 = is10*u00 + is11*u10, su11 = is10*u01 + is11*u11;
    IP[0][0] = ia00 + (t00*su00 + t01*su10);
    IP[0][1] = ia01 + (t00*su01 + t01*su11);
    IP[1][0] = ia10 + (t10*su00 + t11*su10);
    IP[1][1] = ia11 + (t10*su01 + t11*su11);
    IP[0][2] = -(t00*is00 + t01*is10);  IP[0][3] = -(t00*is01 + t01*is11);
    IP[1][2] = -(t10*is00 + t11*is10);  IP[1][3] = -(t10*is01 + t11*is11);
    IP[2][0] = -su00; IP[2][1] = -su01;
    IP[3][0] = -su10; IP[3][1] = -su11;
    IP[2][2] = is00;  IP[2][3] = is01;
    IP[3][2] = is10;  IP[3][3] = is11;
}

// ---------------------------------------------------------------------------
// Backward Riccati. One block (256 thr) per batch. 3 raw barriers/step:
//  R1: M = V*F (96 thr, 4x4, all-b128) || wave 3: prefetch Qt[t-1]/p[t-1]
//      + w = V ft + v; wave 3 ends with counted vmcnt (prev step's loads).
//  R2: Xs = Qt + F^T M (144 thr, 4x4) || qt crew (48 thr, mirrors qu->col 48)
//  R3: ALL 4 waves run the register Gauss-Jordan REDUNDANTLY (wave-local
//      readlane, identical data -> identical results; no KK LDS round-trip).
//      Then, with KK still in registers: lanes 0..31 of wave w compute P7
//      rows 8w..8w+7 of column `lane` (V' = Qxx' - Qxu'*KK); wave 0 writes
//      K/k to global from registers; wave 3 lanes 32..63 compute v'.
// Writes KT[32][16] + k[16] (528 floats) per (b,t).
// ---------------------------------------------------------------------------
__global__ __launch_bounds__(256, 1)
void lqr_backward(const float* __restrict__ Q, const float* __restrict__ p,
                  const float* __restrict__ A, const float* __restrict__ Bm,
                  const float* __restrict__ c1, float* __restrict__ Kws)
{
    const int b   = blockIdx.x;
    const int tid = threadIdx.x;
    const int lane = tid & 63;
    const int wv8  = tid >> 6;               // wave id 0..3

    __shared__ __align__(16) float Fs[32*52];    // F rows, stride 52
    __shared__ __align__(16) float Vs[32*36];    // V, stride 36
    __shared__ __align__(16) float Ms[32*52];    // M = V F, stride 52
    __shared__ __align__(16) float Xs[48*52];    // Qt_new, stride 52 (col48=qu)
    __shared__ __align__(16) float Qtb[2][48*48];// staged Qt double buffer
    __shared__ __align__(16) float qtb[2][256];  // staged p double buffer
    __shared__ float vsv[32], fts[32], wvv[32];

    // hoisted thread-role indices
    const int ai0 = (tid / 12) * 4, ac0 = (tid % 12) * 4;    // R1 (tid<96)
    const int br0 = (tid / 12) * 4, bc0 = (tid % 12) * 4;    // R2 (tid<144)

    // ---- init: F rows, V=0, v=0, ft
    for (int st = tid; st < 256; st += 256) {
        int k = st >> 3, q = st & 7;
        ((float4*)(Fs + k*52))[q] = ((const float4*)A)[(b*32 + k)*8 + q];
    }
    for (int st = tid; st < 128; st += 256) {
        int k = st >> 2, q = st & 3;
        ((float4*)(Fs + k*52))[8 + q] = ((const float4*)Bm)[(b*32 + k)*4 + q];
    }
    for (int st = tid; st < 288; st += 256) ((float4*)Vs)[st] = make_float4(0,0,0,0);
    if (tid < 32) { vsv[tid] = 0.0f; fts[tid] = c1[b*32 + tid]; }

    // ---- stage Qt[127], p[127] into buffer 0
    {
        const float* Qs0 = Q + (size_t)(b*TT + TT-1) * 2304;
        #pragma unroll
        for (int r = 0; r < 3; ++r) {
            int e = r*256 + tid;
            if (e < 576) gload16(Qs0 + e*4, Qtb[0] + e*4);
        }
        if (tid < 12) gload16(p + (size_t)(b*TT + TT-1)*48 + tid*4, qtb[0] + tid*4);
    }
    BARV();

    for (int t = TT-1; t >= 0; --t) {
        const int cur = (TT-1 - t) & 1;
        float* Qtc = Qtb[cur];
        float* qtc = qtb[cur];
        float* Kbase = Kws + (size_t)(b*TT + t) * 528;

        // ========== R1: M = V*F (96 thr, 4x4 tiles, all b128) ||
        //            wave 3: prefetch Qt[t-1]/p[t-1] + w = V ft + v
        if (tid < 96) {
            float4 a0 = make_float4(0,0,0,0), a1 = a0, a2 = a0, a3 = a0;
            #pragma unroll
            for (int k = 0; k < 32; ++k) {
                float4 v = *(const float4*)(Vs + k*36 + ai0);   // V[k][ai0..3]
                float4 f = *(const float4*)(Fs + k*52 + ac0);   // F[k][ac0..3]
                a0.x += v.x*f.x; a0.y += v.x*f.y; a0.z += v.x*f.z; a0.w += v.x*f.w;
                a1.x += v.y*f.x; a1.y += v.y*f.y; a1.z += v.y*f.z; a1.w += v.y*f.w;
                a2.x += v.z*f.x; a2.y += v.z*f.y; a2.z += v.z*f.z; a2.w += v.z*f.w;
                a3.x += v.w*f.x; a3.y += v.w*f.y; a3.z += v.w*f.z; a3.w += v.w*f.w;
            }
            *(float4*)(Ms + (ai0+0)*52 + ac0) = a0;
            *(float4*)(Ms + (ai0+1)*52 + ac0) = a1;
            *(float4*)(Ms + (ai0+2)*52 + ac0) = a2;
            *(float4*)(Ms + (ai0+3)*52 + ac0) = a3;
        } else if (tid >= 192) {
            const int idx = tid - 192;
            if (t > 0) {
                const float* Qs = Q + (size_t)(b*TT + t-1) * 2304;
                float* dst = Qtb[cur ^ 1];
                #pragma unroll
                for (int r = 0; r < 9; ++r) {
                    int e = r*64 + idx;
                    gload16(Qs + e*4, dst + e*4);
                }
                if (idx < 12) gload16(p + (size_t)(b*TT + t-1)*48 + idx*4,
                                      qtb[cur ^ 1] + idx*4);
            }
            if (idx < 32) {
                float acc = vsv[idx];
                #pragma unroll
                for (int k = 0; k < 32; ++k) acc += Vs[idx*36 + k] * fts[k];
                wvv[idx] = acc;
            }
        }
        // wave 3 only: wait for PREVIOUS step's prefetch (10 newer ops stay
        // in flight). At t==0 nothing new was issued -> full drain.
        if (tid >= 192) {
            if (t > 0) asm volatile("s_waitcnt vmcnt(10)" ::: "memory");
            else       asm volatile("s_waitcnt vmcnt(0)"  ::: "memory");
        }
        BAR();

        // ========== R2: Xs = Qt + F^T M (144 thr, 4x4) ||
        //            qt crew (192..239): qtc += F^T w, mirror qu into Xs col 48
        if (tid < 144) {
            float4 a0 = *(const float4*)(Qtc + (br0+0)*48 + bc0);
            float4 a1 = *(const float4*)(Qtc + (br0+1)*48 + bc0);
            float4 a2 = *(const float4*)(Qtc + (br0+2)*48 + bc0);
            float4 a3 = *(const float4*)(Qtc + (br0+3)*48 + bc0);
            #pragma unroll
            for (int k = 0; k < 32; ++k) {
                float4 fr = *(const float4*)(Fs + k*52 + br0);
                float4 mc = *(const float4*)(Ms + k*52 + bc0);
                a0.x += fr.x*mc.x; a0.y += fr.x*mc.y; a0.z += fr.x*mc.z; a0.w += fr.x*mc.w;
                a1.x += fr.y*mc.x; a1.y += fr.y*mc.y; a1.z += fr.y*mc.z; a1.w += fr.y*mc.w;
                a2.x += fr.z*mc.x; a2.y += fr.z*mc.y; a2.z += fr.z*mc.z; a2.w += fr.z*mc.w;
                a3.x += fr.w*mc.x; a3.y += fr.w*mc.y; a3.z += fr.w*mc.z; a3.w += fr.w*mc.w;
            }
            *(float4*)(Xs + (br0+0)*52 + bc0) = a0;
            *(float4*)(Xs + (br0+1)*52 + bc0) = a1;
            *(float4*)(Xs + (br0+2)*52 + bc0) = a2;
            *(float4*)(Xs + (br0+3)*52 + bc0) = a3;
        } else if (tid >= 192 && tid < 240) {
            const int c = tid - 192;
            float acc = qtc[c];
            #pragma unroll
            for (int k = 0; k < 32; ++k) acc += Fs[k*52 + c] * wvv[k];
            qtc[c] = acc;
            if (c >= 32) Xs[c*52 + 48] = acc;   // qu into augmented col 48
        }
        BAR();

        // ========== R3: redundant register GJ on ALL waves, then fused
        //            P7 / K-write / v' straight from registers.
        {
            // lane c owns augmented column c: [Qux(0..31)|Quu(32..47)|qu(48)]
            const int c = (lane < 49) ? lane : 48;
            float col[16];
            #pragma unroll
            for (int r = 0; r < 16; ++r) col[r] = Xs[(32+r)*52 + c];

            #pragma unroll
            for (int q = 0; q < 4; ++q) {
                const int pc = 32 + 4*q;     // pivot column lanes
                float4 pr[4];
                #pragma unroll
                for (int m = 0; m < 4; ++m) {
                    pr[m].x = rdlane(col[4*q+m], pc+0);
                    pr[m].y = rdlane(col[4*q+m], pc+1);
                    pr[m].z = rdlane(col[4*q+m], pc+2);
                    pr[m].w = rdlane(col[4*q+m], pc+3);
                }
                float IP[4][4];
                inv4(pr, IP);
                float R[4];
                #pragma unroll
                for (int m = 0; m < 4; ++m)
                    R[m] = IP[m][0]*col[4*q+0] + IP[m][1]*col[4*q+1]
                         + IP[m][2]*col[4*q+2] + IP[m][3]*col[4*q+3];
                #pragma unroll
                for (int r = 0; r < 16; ++r) {
                    if ((r >> 2) == q) continue;
                    float f0 = rdlane(col[r], pc+0);
                    float f1 = rdlane(col[r], pc+1);
                    float f2 = rdlane(col[r], pc+2);
                    float f3 = rdlane(col[r], pc+3);
                    col[r] -= f0*R[0] + f1*R[1] + f2*R[2] + f3*R[3];
                }
                #pragma unroll
                for (int m = 0; m < 4; ++m) col[4*q+m] = R[m];
            }
            // col[r] now = KK[r][c] (c<32), or Quu^-1 cols (32..47), or kk (48)

            // --- wave 0: K/k global write from registers
            if (tid < 32) {
                float* kb = Kbase + tid*16;          // KT[state c][ctrl 0..15]
                *(float4*)(kb+ 0) = make_float4(-col[0],-col[1],-col[2],-col[3]);
                *(float4*)(kb+ 4) = make_float4(-col[4],-col[5],-col[6],-col[7]);
                *(float4*)(kb+ 8) = make_float4(-col[8],-col[9],-col[10],-col[11]);
                *(float4*)(kb+12) = make_float4(-col[12],-col[13],-col[14],-col[15]);
            } else if (tid == 48) {
                float* kb = Kbase + 512;             // k[ctrl 0..15]
                *(float4*)(kb+ 0) = make_float4(-col[0],-col[1],-col[2],-col[3]);
                *(float4*)(kb+ 4) = make_float4(-col[4],-col[5],-col[6],-col[7]);
                *(float4*)(kb+ 8) = make_float4(-col[8],-col[9],-col[10],-col[11]);
                *(float4*)(kb+12) = make_float4(-col[12],-col[13],-col[14],-col[15]);
            }

            // --- P7: lane j (<32) of wave w computes V' rows 8w..8w+7, col j
            if (lane < 32) {
                const int j = lane;
                #pragma unroll
                for (int ii = 0; ii < 8; ++ii) {
                    const int i = wv8*8 + ii;
                    float4 q0 = *(const float4*)(Xs + i*52 + 32);
                    float4 q1 = *(const float4*)(Xs + i*52 + 36);
                    float4 q2 = *(const float4*)(Xs + i*52 + 40);
                    float4 q3 = *(const float4*)(Xs + i*52 + 44);
                    float acc = Xs[i*52 + j];
                    acc -= q0.x*col[0]  + q0.y*col[1]  + q0.z*col[2]  + q0.w*col[3];
                    acc -= q1.x*col[4]  + q1.y*col[5]  + q1.z*col[6]  + q1.w*col[7];
                    acc -= q2.x*col[8]  + q2.y*col[9]  + q2.z*col[10] + q2.w*col[11];
                    acc -= q3.x*col[12] + q3.y*col[13] + q3.z*col[14] + q3.w*col[15];
                    Vs[i*36 + j] = acc;
                }
            } else if (tid >= 224) {
                // --- v': wave 3 lanes 32..63, i = tid-224
                const int i = tid - 224;
                float kkr[16];
                #pragma unroll
                for (int r = 0; r < 16; ++r) kkr[r] = rdlane(col[r], 48);
                float accv = qtc[i];
                #pragma unroll
                for (int k = 0; k < 16; ++k)
                    accv -= Xs[i*52 + 32 + k] * kkr[k];
                vsv[i] = accv;
            }
        }
        BAR();   // end of step (prefetch stays in flight; stores need no drain)
    }
}

// ---------------------------------------------------------------------------
// Forward rollout, one wave per batch, register-prefetched K.
// ---------------------------------------------------------------------------
__global__ __launch_bounds__(64, 1)
void lqr_forward(const float* __restrict__ Kws, const float* __restrict__ A,
                 const float* __restrict__ Bm, const float* __restrict__ c1,
                 const float* __restrict__ x_init,
                 float* __restrict__ xs, float* __restrict__ us,
                 float* __restrict__ taus)
{
    const int b = blockIdx.x, l = threadIdx.x;
    __shared__ __align__(16) float Fb[32*48];
    __shared__ __align__(16) float Kb[544];
    __shared__ float c1s[32], xu[48];

    for (int st = l; st < 256; st += 64) {
        int k = st >> 3, q = st & 7;
        ((float4*)Fb)[k*12 + q] = ((const float4*)A)[(b*32 + k)*8 + q];
    }
    for (int st = l; st < 128; st += 64) {
        int k = st >> 2, q = st & 3;
        ((float4*)Fb)[k*12 + 8 + q] = ((const float4*)Bm)[(b*32 + k)*4 + q];
    }
    if (l < 32) { c1s[l] = c1[b*32 + l]; xu[l] = x_init[b*32 + l]; }

    // preload K[0]
    float4 ka, kb, kc = make_float4(0,0,0,0);
    {
        const float4* s0 = (const float4*)(Kws + (size_t)(b*TT) * 528);
        ka = s0[l]; kb = s0[l + 64];
        if (l < 4) kc = s0[l + 128];
    }
    __syncthreads();

    for (int t = 0; t < TT; ++t) {
        ((float4*)Kb)[l]      = ka;
        ((float4*)Kb)[l + 64] = kb;
        if (l < 4) ((float4*)Kb)[l + 128] = kc;
        __syncthreads();

        // prefetch K[t+1]
        if (t + 1 < TT) {
            const float4* sn = (const float4*)(Kws + (size_t)(b*TT + t+1) * 528);
            ka = sn[l]; kb = sn[l + 64];
            if (l < 4) kc = sn[l + 128];
        }

        // u = K x + k   (KT stored as [j][i])
        float part = 0.0f;
        int i = l & 15, g = l >> 4;
        #pragma unroll
        for (int jj = 0; jj < 8; ++jj) {
            int j = g*8 + jj;
            part += Kb[j*16 + i] * xu[j];
        }
        part += __shfl_down(part, 32);
        part += __shfl_down(part, 16);
        float ui = part + Kb[512 + i];
        if (l < 16) {
            xu[32 + l] = ui;
            us[(size_t)(t*64 + b)*16 + l] = ui;
        }
        __syncthreads();

        if (l < 32) xs[(size_t)(t*64 + b)*32 + l] = xu[l];
        if (l < 48) taus[(size_t)(t*64 + b)*48 + l] = xu[l];

        // xn = F xu + c1
        float pn = 0.0f;
        int i2 = l & 31, h = l >> 5;
        #pragma unroll
        for (int jj = 0; jj < 24; ++jj) {
            int j = h*24 + jj;
            pn += Fb[i2*48 + j] * xu[j];
        }
        pn += __shfl_down(pn, 32);
        float xni = pn + ((l < 32) ? c1s[i2] : 0.0f);
        __syncthreads();
        if (l < 32) xu[l] = xni;
        __syncthreads();
    }
}

// ---------------------------------------------------------------------------
// objs[t,b] = 0.5*xu^T Q xu + xu.p   (fully parallel, mem-bound)
// ---------------------------------------------------------------------------
__global__ __launch_bounds__(256, 4)
void lqr_obj(const float* __restrict__ Q, const float* __restrict__ p,
             const float* __restrict__ taus, float* __restrict__ objs)
{
    const int bi = blockIdx.x;            // = b*T + t
    const int b = bi >> 7, t = bi & 127;
    const int tid = threadIdx.x;
    __shared__ float xu[48];
    __shared__ float red[8];
    const float* tp = taus + (size_t)(t*64 + b)*48;
    if (tid < 48) xu[tid] = tp[tid];
    __syncthreads();

    const float4* Q4 = (const float4*)(Q + (size_t)bi * 2304);
    float acc = 0.0f;
    for (int e4 = tid; e4 < 576; e4 += 256) {
        float4 qv = Q4[e4];
        int r = e4 / 12, c = (e4 % 12) * 4;
        float xr = xu[r];
        acc += xr * (qv.x*xu[c] + qv.y*xu[c+1] + qv.z*xu[c+2] + qv.w*xu[c+3]);
    }
    acc *= 0.5f;
    if (tid < 48) acc += xu[tid] * p[(size_t)bi*48 + tid];

    #pragma unroll
    for (int off = 32; off > 0; off >>= 1) acc += __shfl_down(acc, off);
    if ((tid & 63) == 0) red[tid >> 6] = acc;
    __syncthreads();
    if (tid == 0) objs[(t << 6) + b] = red[0] + red[1] + red[2] + red[3];
}

// ---------------------------------------------------------------------------
extern "C" void kernel_launch(void* const* d_in, const int* in_sizes, int n_in,
                              void* d_out, int out_size, void* d_ws, size_t ws_size,
                              hipStream_t stream) {
    const float* x_init = (const float*)d_in[0];
    const float* Q      = (const float*)d_in[1];
    const float* p      = (const float*)d_in[2];
    const float* A      = (const float*)d_in[3];
    const float* Bm     = (const float*)d_in[4];
    const float* c1     = (const float*)d_in[5];

    float* out  = (float*)d_out;
    float* xs   = out;                       // 128*64*32 = 262144
    float* us   = out + 262144;              // 128*64*16 = 131072
    float* objs = out + 393216;              // 128*64    = 8192
    float* taus = out + 401408;              // 128*64*48 = 393216

    float* Kws = (float*)d_ws;               // 64*128*528 floats = 17.3 MB

    lqr_backward<<<NBATCH, 256, 0, stream>>>(Q, p, A, Bm, c1, Kws);
    lqr_forward<<<NBATCH, 64, 0, stream>>>(Kws, A, Bm, c1, x_init, xs, us, taus);
    lqr_obj<<<NBATCH*TT, 256, 0, stream>>>(Q, p, taus, objs);
}

// Round 14
// 682.136 us; speedup vs baseline: 1.0491x; 1.0491x over previous
//
#include <hip/hip_runtime.h>

#define TT     128
#define NBATCH 64

// raw barrier: drain this wave's LDS ops, then barrier. No vmcnt drain --
// keeps async Qt prefetch in flight across phases.
#define BAR()  asm volatile("s_waitcnt lgkmcnt(0)\n\ts_barrier" ::: "memory")
#define BARV() asm volatile("s_waitcnt vmcnt(0) lgkmcnt(0)\n\ts_barrier" ::: "memory")

__device__ __forceinline__ void gload16(const float* g, float* l) {
    __builtin_amdgcn_global_load_lds(
        (__attribute__((address_space(1))) void*)g,
        (__attribute__((address_space(3))) void*)l, 16, 0, 0);
}

// SALU broadcast: read lane `l`'s value of v (l compile-time constant)
__device__ __forceinline__ float rdlane(float v, int l) {
    return __int_as_float(__builtin_amdgcn_readlane(__float_as_int(v), l));
}

// closed-form 4x4 inverse via 2x2 blocks (SPD pivot blocks, no pivoting)
__device__ __forceinline__ void inv4(const float4 pr[4], float IP[4][4]) {
    float a00=pr[0].x, a01=pr[0].y, a10=pr[1].x, a11=pr[1].y;
    float b00=pr[0].z, b01=pr[0].w, b10=pr[1].z, b11=pr[1].w;
    float c00=pr[2].x, c01=pr[2].y, c10=pr[3].x, c11=pr[3].y;
    float d00=pr[2].z, d01=pr[2].w, d10=pr[3].z, d11=pr[3].w;
    float r = 1.0f / (a00*a11 - a01*a10);
    float ia00 =  a11*r, ia01 = -a01*r, ia10 = -a10*r, ia11 = a00*r;
    float t00 = ia00*b00 + ia01*b10, t01 = ia00*b01 + ia01*b11;
    float t10 = ia10*b00 + ia11*b10, t11 = ia10*b01 + ia11*b11;
    float u00 = c00*ia00 + c01*ia10, u01 = c00*ia01 + c01*ia11;
    float u10 = c10*ia00 + c11*ia10, u11 = c10*ia01 + c11*ia11;
    float s00 = d00 - (c00*t00 + c01*t10), s01 = d01 - (c00*t01 + c01*t11);
    float s10 = d10 - (c10*t00 + c11*t10), s11 = d11 - (c10*t01 + c11*t11);
    float rs = 1.0f / (s00*s11 - s01*s10);
    float is00 =  s11*rs, is01 = -s01*rs, is10 = -s10*rs, is11 = s00*rs;
    float su00 = is00*u00 + is01*u10, su01 = is00*u01 + is01*u11;
    float su10 = is10*u00 + is11*u10, su11 = is10*u01 + is11*u11;
    IP[0][0] = ia00 + (t00*su00 + t01*su10);
    IP[0][1] = ia01 + (t00*su01 + t01*su11);
    IP[1][0] = ia10 + (t10*su00 + t11*su10);
    IP[1][1] = ia11 + (t10*su01 + t11*su11);
    IP[0][2] = -(t00*is00 + t01*is10);  IP[0][3] = -(t00*is01 + t01*is11);
    IP[1][2] = -(t10*is00 + t11*is10);  IP[1][3] = -(t10*is01 + t11*is11);
    IP[2][0] = -su00; IP[2][1] = -su01;
    IP[3][0] = -su10; IP[3][1] = -su11;
    IP[2][2] = is00;  IP[2][3] = is01;
    IP[3][2] = is10;  IP[3][3] = is11;
}

// ---------------------------------------------------------------------------
// Backward Riccati. One block (256 thr) per batch. 4 raw barriers/step:
//  R1: A (M = V*F, 96 thr 4x4 all-b128) | wave 3: prefetch Qt[t-1] + w
//  R2: B (Xs = Qt + F^T M, 144 thr 4x4) | qt crew (48 thr)
//  R3: wave 0: register Gauss-Jordan on [Qux|Quu|qu] via readlane broadcast,
//      writes KK to LDS + K/k to global || tid 64..255: preload P7 operands
//  R4: ALL 256 thr: V' = Qxx' - Qxu'*KK (1 row x 4 cols each); pg==0: v'
// Writes KT[32][16] + k[16] (528 floats) per (b,t).
// ---------------------------------------------------------------------------
__global__ __launch_bounds__(256, 1)
void lqr_backward(const float* __restrict__ Q, const float* __restrict__ p,
                  const float* __restrict__ A, const float* __restrict__ Bm,
                  const float* __restrict__ c1, float* __restrict__ Kws)
{
    const int b   = blockIdx.x;
    const int tid = threadIdx.x;

    __shared__ __align__(16) float Fs[32*52];    // F rows, stride 52
    __shared__ __align__(16) float Vs[32*36];    // V, stride 36
    __shared__ __align__(16) float Ms[32*52];    // M = V F, stride 52
    __shared__ __align__(16) float Xs[48*52];    // Qt_new, stride 52
    __shared__ __align__(16) float Qtb[2][48*48];// staged Qt double buffer
    __shared__ __align__(16) float qtb[2][256];  // staged p double buffer
    __shared__ __align__(16) float KKs[16*36];   // Quu^-1 [Qux | qu], kk at 32
    __shared__ float vsv[32], fts[32], wv[32];

    // hoisted thread-role indices
    const int ai0 = (tid / 12) * 4, ac0 = (tid % 12) * 4;    // phase A (tid<96)
    const int br0 = (tid / 12) * 4, bc0 = (tid % 12) * 4;    // phase B (tid<144)
    const int pi  = tid >> 3;                                // P7 row 0..31
    const int pg  = tid & 7;                                 // P7 col group
    const int pj0 = pg * 4;                                  // P7 col base 0..28

    // ---- init: F rows, V=0, v=0, ft
    for (int st = tid; st < 256; st += 256) {
        int k = st >> 3, q = st & 7;
        ((float4*)(Fs + k*52))[q] = ((const float4*)A)[(b*32 + k)*8 + q];
    }
    for (int st = tid; st < 128; st += 256) {
        int k = st >> 2, q = st & 3;
        ((float4*)(Fs + k*52))[8 + q] = ((const float4*)Bm)[(b*32 + k)*4 + q];
    }
    for (int st = tid; st < 288; st += 256) ((float4*)Vs)[st] = make_float4(0,0,0,0);
    if (tid < 32) { vsv[tid] = 0.0f; fts[tid] = c1[b*32 + tid]; }

    // ---- stage Qt[127], p[127] into buffer 0
    {
        const float* Qs0 = Q + (size_t)(b*TT + TT-1) * 2304;
        #pragma unroll
        for (int r = 0; r < 3; ++r) {
            int e = r*256 + tid;
            if (e < 576) gload16(Qs0 + e*4, Qtb[0] + e*4);
        }
        if (tid < 12) gload16(p + (size_t)(b*TT + TT-1)*48 + tid*4, qtb[0] + tid*4);
    }
    BARV();

    for (int t = TT-1; t >= 0; --t) {
        const int cur = (TT-1 - t) & 1;
        float* Qtc = Qtb[cur];
        float* qtc = qtb[cur];
        float* Kbase = Kws + (size_t)(b*TT + t) * 528;

        // ========== R1: A: M = V*F (96 thr, 4x4 tiles, all b128) ||
        //            wave 3: prefetch Qt[t-1]/p[t-1] + w = V ft + v
        if (tid < 96) {
            float4 a0 = make_float4(0,0,0,0), a1 = a0, a2 = a0, a3 = a0;
            #pragma unroll
            for (int k = 0; k < 32; ++k) {
                float4 v = *(const float4*)(Vs + k*36 + ai0);   // V[k][ai0..3]
                float4 f = *(const float4*)(Fs + k*52 + ac0);   // F[k][ac0..3]
                a0.x += v.x*f.x; a0.y += v.x*f.y; a0.z += v.x*f.z; a0.w += v.x*f.w;
                a1.x += v.y*f.x; a1.y += v.y*f.y; a1.z += v.y*f.z; a1.w += v.y*f.w;
                a2.x += v.z*f.x; a2.y += v.z*f.y; a2.z += v.z*f.z; a2.w += v.z*f.w;
                a3.x += v.w*f.x; a3.y += v.w*f.y; a3.z += v.w*f.z; a3.w += v.w*f.w;
            }
            *(float4*)(Ms + (ai0+0)*52 + ac0) = a0;
            *(float4*)(Ms + (ai0+1)*52 + ac0) = a1;
            *(float4*)(Ms + (ai0+2)*52 + ac0) = a2;
            *(float4*)(Ms + (ai0+3)*52 + ac0) = a3;
        } else if (tid >= 192) {
            const int idx = tid - 192;
            if (t > 0) {
                const float* Qs = Q + (size_t)(b*TT + t-1) * 2304;
                float* dst = Qtb[cur ^ 1];
                #pragma unroll
                for (int r = 0; r < 9; ++r) {
                    int e = r*64 + idx;
                    gload16(Qs + e*4, dst + e*4);
                }
                if (idx < 12) gload16(p + (size_t)(b*TT + t-1)*48 + idx*4,
                                      qtb[cur ^ 1] + idx*4);
            }
            if (idx < 32) {
                float acc = vsv[idx];
                #pragma unroll
                for (int k = 0; k < 32; ++k) acc += Vs[idx*36 + k] * fts[k];
                wv[idx] = acc;
            }
        }
        BAR();

        // ========== R2: B: Xs = Qt + F^T M (144 thr, 4x4) ||
        //            qt crew (192..239): qtc += F^T w, mirror qu into Xs col 48
        if (tid < 144) {
            float4 a0 = *(const float4*)(Qtc + (br0+0)*48 + bc0);
            float4 a1 = *(const float4*)(Qtc + (br0+1)*48 + bc0);
            float4 a2 = *(const float4*)(Qtc + (br0+2)*48 + bc0);
            float4 a3 = *(const float4*)(Qtc + (br0+3)*48 + bc0);
            #pragma unroll
            for (int k = 0; k < 32; ++k) {
                float4 fr = *(const float4*)(Fs + k*52 + br0);
                float4 mc = *(const float4*)(Ms + k*52 + bc0);
                a0.x += fr.x*mc.x; a0.y += fr.x*mc.y; a0.z += fr.x*mc.z; a0.w += fr.x*mc.w;
                a1.x += fr.y*mc.x; a1.y += fr.y*mc.y; a1.z += fr.y*mc.z; a1.w += fr.y*mc.w;
                a2.x += fr.z*mc.x; a2.y += fr.z*mc.y; a2.z += fr.z*mc.z; a2.w += fr.z*mc.w;
                a3.x += fr.w*mc.x; a3.y += fr.w*mc.y; a3.z += fr.w*mc.z; a3.w += fr.w*mc.w;
            }
            *(float4*)(Xs + (br0+0)*52 + bc0) = a0;
            *(float4*)(Xs + (br0+1)*52 + bc0) = a1;
            *(float4*)(Xs + (br0+2)*52 + bc0) = a2;
            *(float4*)(Xs + (br0+3)*52 + bc0) = a3;
        } else if (tid >= 192 && tid < 240) {
            const int c = tid - 192;
            float acc = qtc[c];
            #pragma unroll
            for (int k = 0; k < 32; ++k) acc += Fs[k*52 + c] * wv[k];
            qtc[c] = acc;
            if (c >= 32) Xs[c*52 + 48] = acc;   // qu into augmented col 48
        }
        BAR();

        // ========== R3: wave 0: register GJ | tid 64..255: P7 preload
        float4 pa0; float pq[16];
        if (tid < 64) {
            // lane c owns augmented column c: [Qux(0..31)|Quu(32..47)|qu(48)]
            const int c = (tid < 49) ? tid : 48;
            float col[16];
            #pragma unroll
            for (int r = 0; r < 16; ++r) col[r] = Xs[(32+r)*52 + c];

            #pragma unroll
            for (int q = 0; q < 4; ++q) {
                const int pc = 32 + 4*q;     // pivot column lanes
                float4 pr[4];
                #pragma unroll
                for (int m = 0; m < 4; ++m) {
                    pr[m].x = rdlane(col[4*q+m], pc+0);
                    pr[m].y = rdlane(col[4*q+m], pc+1);
                    pr[m].z = rdlane(col[4*q+m], pc+2);
                    pr[m].w = rdlane(col[4*q+m], pc+3);
                }
                float IP[4][4];
                inv4(pr, IP);
                float R[4];
                #pragma unroll
                for (int m = 0; m < 4; ++m)
                    R[m] = IP[m][0]*col[4*q+0] + IP[m][1]*col[4*q+1]
                         + IP[m][2]*col[4*q+2] + IP[m][3]*col[4*q+3];
                #pragma unroll
                for (int r = 0; r < 16; ++r) {
                    if ((r >> 2) == q) continue;
                    float f0 = rdlane(col[r], pc+0);
                    float f1 = rdlane(col[r], pc+1);
                    float f2 = rdlane(col[r], pc+2);
                    float f3 = rdlane(col[r], pc+3);
                    col[r] -= f0*R[0] + f1*R[1] + f2*R[2] + f3*R[3];
                }
                #pragma unroll
                for (int m = 0; m < 4; ++m) col[4*q+m] = R[m];
            }

            // write KK to LDS (stride 36; kk at col slot 32) + K/k to global
            if (tid < 32) {
                #pragma unroll
                for (int r = 0; r < 16; ++r) {
                    KKs[r*36 + c]    = col[r];
                    Kbase[c*16 + r]  = -col[r];       // KT[state][ctrl]
                }
            } else if (tid == 48) {
                #pragma unroll
                for (int r = 0; r < 16; ++r) {
                    KKs[r*36 + 32]   = col[r];
                    Kbase[512 + r]   = -col[r];       // k[ctrl]
                }
            }
        } else {
            // P7 preload: row pi, cols pj0..pj0+3 + Qxu row pi
            pa0 = *(const float4*)(Xs + pi*52 + pj0);
            #pragma unroll
            for (int m = 0; m < 4; ++m) {
                float4 v4 = *(const float4*)(Xs + pi*52 + 32 + m*4);
                pq[m*4+0] = v4.x; pq[m*4+1] = v4.y;
                pq[m*4+2] = v4.z; pq[m*4+3] = v4.w;
            }
        }
        BAR();

        // ========== R4: ALL: V' = Qxx' - Qxu'*KK (1 row x 4 cols) ; pg==0: v'
        {
            if (tid < 64) {   // GJ wave loads its P7 operands now
                pa0 = *(const float4*)(Xs + pi*52 + pj0);
                #pragma unroll
                for (int m = 0; m < 4; ++m) {
                    float4 v4 = *(const float4*)(Xs + pi*52 + 32 + m*4);
                    pq[m*4+0] = v4.x; pq[m*4+1] = v4.y;
                    pq[m*4+2] = v4.z; pq[m*4+3] = v4.w;
                }
            }
            #pragma unroll
            for (int k = 0; k < 16; ++k) {
                float4 k0 = *(const float4*)(KKs + k*36 + pj0);
                pa0.x -= pq[k]*k0.x; pa0.y -= pq[k]*k0.y;
                pa0.z -= pq[k]*k0.z; pa0.w -= pq[k]*k0.w;
            }
            *(float4*)(Vs + pi*36 + pj0) = pa0;
            if (pg == 0) {
                float accv = qtc[pi];
                #pragma unroll
                for (int k = 0; k < 16; ++k) accv -= pq[k] * KKs[k*36 + 32];
                vsv[pi] = accv;
            }
        }
        BARV();   // drains this step's prefetch loads + K stores
    }
}

// ---------------------------------------------------------------------------
// Forward rollout, one wave per batch, register-prefetched K.
// ---------------------------------------------------------------------------
__global__ __launch_bounds__(64, 1)
void lqr_forward(const float* __restrict__ Kws, const float* __restrict__ A,
                 const float* __restrict__ Bm, const float* __restrict__ c1,
                 const float* __restrict__ x_init,
                 float* __restrict__ xs, float* __restrict__ us,
                 float* __restrict__ taus)
{
    const int b = blockIdx.x, l = threadIdx.x;
    __shared__ __align__(16) float Fb[32*48];
    __shared__ __align__(16) float Kb[544];
    __shared__ float c1s[32], xu[48];

    for (int st = l; st < 256; st += 64) {
        int k = st >> 3, q = st & 7;
        ((float4*)Fb)[k*12 + q] = ((const float4*)A)[(b*32 + k)*8 + q];
    }
    for (int st = l; st < 128; st += 64) {
        int k = st >> 2, q = st & 3;
        ((float4*)Fb)[k*12 + 8 + q] = ((const float4*)Bm)[(b*32 + k)*4 + q];
    }
    if (l < 32) { c1s[l] = c1[b*32 + l]; xu[l] = x_init[b*32 + l]; }

    // preload K[0]
    float4 ka, kb, kc = make_float4(0,0,0,0);
    {
        const float4* s0 = (const float4*)(Kws + (size_t)(b*TT) * 528);
        ka = s0[l]; kb = s0[l + 64];
        if (l < 4) kc = s0[l + 128];
    }
    __syncthreads();

    for (int t = 0; t < TT; ++t) {
        ((float4*)Kb)[l]      = ka;
        ((float4*)Kb)[l + 64] = kb;
        if (l < 4) ((float4*)Kb)[l + 128] = kc;
        __syncthreads();

        // prefetch K[t+1]
        if (t + 1 < TT) {
            const float4* sn = (const float4*)(Kws + (size_t)(b*TT + t+1) * 528);
            ka = sn[l]; kb = sn[l + 64];
            if (l < 4) kc = sn[l + 128];
        }

        // u = K x + k   (KT stored as [j][i])
        float part = 0.0f;
        int i = l & 15, g = l >> 4;
        #pragma unroll
        for (int jj = 0; jj < 8; ++jj) {
            int j = g*8 + jj;
            part += Kb[j*16 + i] * xu[j];
        }
        part += __shfl_down(part, 32);
        part += __shfl_down(part, 16);
        float ui = part + Kb[512 + i];
        if (l < 16) {
            xu[32 + l] = ui;
            us[(size_t)(t*64 + b)*16 + l] = ui;
        }
        __syncthreads();

        if (l < 32) xs[(size_t)(t*64 + b)*32 + l] = xu[l];
        if (l < 48) taus[(size_t)(t*64 + b)*48 + l] = xu[l];

        // xn = F xu + c1
        float pn = 0.0f;
        int i2 = l & 31, h = l >> 5;
        #pragma unroll
        for (int jj = 0; jj < 24; ++jj) {
            int j = h*24 + jj;
            pn += Fb[i2*48 + j] * xu[j];
        }
        pn += __shfl_down(pn, 32);
        float xni = pn + ((l < 32) ? c1s[i2] : 0.0f);
        __syncthreads();
        if (l < 32) xu[l] = xni;
        __syncthreads();
    }
}

// ---------------------------------------------------------------------------
// objs[t,b] = 0.5*xu^T Q xu + xu.p   (fully parallel, mem-bound)
// ---------------------------------------------------------------------------
__global__ __launch_bounds__(256, 4)
void lqr_obj(const float* __restrict__ Q, const float* __restrict__ p,
             const float* __restrict__ taus, float* __restrict__ objs)
{
    const int bi = blockIdx.x;            // = b*T + t
    const int b = bi >> 7, t = bi & 127;
    const int tid = threadIdx.x;
    __shared__ float xu[48];
    __shared__ float red[8];
    const float* tp = taus + (size_t)(t*64 + b)*48;
    if (tid < 48) xu[tid] = tp[tid];
    __syncthreads();

    const float4* Q4 = (const float4*)(Q + (size_t)bi * 2304);
    float acc = 0.0f;
    for (int e4 = tid; e4 < 576; e4 += 256) {
        float4 qv = Q4[e4];
        int r = e4 / 12, c = (e4 % 12) * 4;
        float xr = xu[r];
        acc += xr * (qv.x*xu[c] + qv.y*xu[c+1] + qv.z*xu[c+2] + qv.w*xu[c+3]);
    }
    acc *= 0.5f;
    if (tid < 48) acc += xu[tid] * p[(size_t)bi*48 + tid];

    #pragma unroll
    for (int off = 32; off > 0; off >>= 1) acc += __shfl_down(acc, off);
    if ((tid & 63) == 0) red[tid >> 6] = acc;
    __syncthreads();
    if (tid == 0) objs[(t << 6) + b] = red[0] + red[1] + red[2] + red[3];
}

// ---------------------------------------------------------------------------
extern "C" void kernel_launch(void* const* d_in, const int* in_sizes, int n_in,
                              void* d_out, int out_size, void* d_ws, size_t ws_size,
                              hipStream_t stream) {
    const float* x_init = (const float*)d_in[0];
    const float* Q      = (const float*)d_in[1];
    const float* p      = (const float*)d_in[2];
    const float* A      = (const float*)d_in[3];
    const float* Bm     = (const float*)d_in[4];
    const float* c1     = (const float*)d_in[5];

    float* out  = (float*)d_out;
    float* xs   = out;                       // 128*64*32 = 262144
    float* us   = out + 262144;              // 128*64*16 = 131072
    float* objs = out + 393216;              // 128*64    = 8192
    float* taus = out + 401408;              // 128*64*48 = 393216

    float* Kws = (float*)d_ws;               // 64*128*528 floats = 17.3 MB

    lqr_backward<<<NBATCH, 256, 0, stream>>>(Q, p, A, Bm, c1, Kws);
    lqr_forward<<<NBATCH, 64, 0, stream>>>(Kws, A, Bm, c1, x_init, xs, us, taus);
    lqr_obj<<<NBATCH*TT, 256, 0, stream>>>(Q, p, taus, objs);
}